// Round 17
// baseline (3801.903 us; speedup 1.0000x reference)
//
#include <hip/hip_runtime.h>
#include <hip/hip_bf16.h>
#include <stdint.h>

#define H 2048
#define FOURH 8192
#define NT 768
#define NS 256

typedef __attribute__((ext_vector_type(8))) short bf16x8;
typedef __attribute__((ext_vector_type(4))) float f32x4;
typedef __attribute__((ext_vector_type(4))) unsigned uint4v;
typedef __attribute__((ext_vector_type(2))) unsigned uint2v;
typedef _Float16 f16x2 __attribute__((ext_vector_type(2)));

static __device__ __forceinline__ unsigned short f2bf(float x) {
  unsigned u = __float_as_uint(x);
  return (unsigned short)((u + 0x7fffu + ((u >> 16) & 1u)) >> 16);
}
static __device__ __forceinline__ unsigned pk2(float lo, float hi) {
  return ((unsigned)f2bf(hi) << 16) | (unsigned)f2bf(lo);
}
static __device__ __forceinline__ unsigned pkf16(float lo, float hi) {
  auto h = __builtin_amdgcn_cvt_pkrtz(lo, hi);  // __fp16 ext_vector(2)
  return __builtin_bit_cast(unsigned, h);
}
static __device__ __forceinline__ float sigm(float x) { return 1.f / (1.f + __expf(-x)); }
static __device__ __forceinline__ float tanh_fast(float x) {
  float xc = fminf(fmaxf(x, -15.f), 15.f);
  float e = __expf(2.f * xc);
  return (e - 1.f) / (e + 1.f);
}

// dot2: acc += w.x*h.x + w.y*h.y with packed f16 operands
static __device__ __forceinline__ float dot2(unsigned w, unsigned h, float acc) {
#if __has_builtin(__builtin_amdgcn_fdot2)
  return __builtin_amdgcn_fdot2(__builtin_bit_cast(f16x2, w),
                                __builtin_bit_cast(f16x2, h), acc, false);
#else
  f16x2 wv = __builtin_bit_cast(f16x2, w);
  f16x2 hv = __builtin_bit_cast(f16x2, h);
  return acc + (float)wv.x * (float)hv.x + (float)wv.y * (float)hv.y;
#endif
}

// one-immediate-pattern xor swizzle (BitMode: offset = xor<<10 | 0x1F)
template <int PAT>
static __device__ __forceinline__ float swz(float v) {
  return __int_as_float(__builtin_amdgcn_ds_swizzle(__float_as_int(v), PAT));
}
// full 64-lane xor-butterfly sum
static __device__ __forceinline__ float wave_sum(float v) {
  v += swz<0x041F>(v);          // xor 1
  v += swz<0x081F>(v);          // xor 2
  v += swz<0x101F>(v);          // xor 4
  v += swz<0x201F>(v);          // xor 8
  v += swz<0x401F>(v);          // xor 16
  v += __shfl_xor(v, 32, 64);   // xor 32 (crosses 32-lane groups)
  return v;
}

// ---------------- gather: build X_bf16[768][2048] ----------------
__global__ void gather_x(const int* __restrict__ ctx, const int* __restrict__ f1,
                         const int* __restrict__ f2, const float* __restrict__ ctx_table,
                         const float* __restrict__ face_table, unsigned short* __restrict__ X) {
  int t = blockIdx.x;            // 0..767
  int s = t / 3, k = t - 3 * s;  // sample, sub-step
  const float* src;
  if (k == 0)      src = ctx_table  + (size_t)ctx[s] * H;
  else if (k == 1) src = face_table + (size_t)f1[s] * H;
  else             src = face_table + (size_t)f2[s] * H;
  int c = threadIdx.x * 8;
  float4 v0 = *(const float4*)(src + c);
  float4 v1 = *(const float4*)(src + c + 4);
  uint4 o;
  o.x = pk2(v0.x, v0.y); o.y = pk2(v0.z, v0.w);
  o.z = pk2(v1.x, v1.y); o.w = pk2(v1.z, v1.w);
  *(uint4*)(X + (size_t)t * H + c) = o;
}

// ---------------- GEMM: P[768][8192] = X @ W_ih^T + (b_ih + b_hh) ----------------
__launch_bounds__(256)
__global__ void gemm_p(const unsigned short* __restrict__ X, const float* __restrict__ Wih,
                       const float* __restrict__ bih, const float* __restrict__ bhh,
                       float* __restrict__ P) {
  __shared__ unsigned short Alds[128 * 32];
  __shared__ unsigned short Blds[128 * 32];
  int tid = threadIdx.x;
  int bm = (blockIdx.x >> 6) * 128;   // 6 M-tiles
  int bn = (blockIdx.x & 63) * 128;   // 64 N-tiles
  int w = tid >> 6, l = tid & 63;
  int wm = (w >> 1) * 64, wn = (w & 1) * 64;
  int sr = tid >> 1;             // staging row 0..127
  int sc = (tid & 1) * 16;       // staging col 0 / 16
  int cl = l & 15, kg = (l >> 4) * 8;

  f32x4 acc[4][4];
#pragma unroll
  for (int i = 0; i < 4; ++i)
#pragma unroll
    for (int j = 0; j < 4; ++j) acc[i][j] = (f32x4){0.f, 0.f, 0.f, 0.f};

  for (int kt = 0; kt < H; kt += 32) {
    __syncthreads();
    const unsigned short* ap = X + (size_t)(bm + sr) * H + kt + sc;
    uint4 a0 = *(const uint4*)ap;
    uint4 a1 = *(const uint4*)(ap + 8);
    const float* bp = Wih + (size_t)(bn + sr) * H + kt + sc;
    float4 f0 = *(const float4*)bp;
    float4 f1v = *(const float4*)(bp + 4);
    float4 f2v = *(const float4*)(bp + 8);
    float4 f3v = *(const float4*)(bp + 12);
    *(uint4*)(Alds + sr * 32 + sc) = a0;
    *(uint4*)(Alds + sr * 32 + sc + 8) = a1;
    uint4 b0, b1;
    b0.x = pk2(f0.x, f0.y);  b0.y = pk2(f0.z, f0.w);
    b0.z = pk2(f1v.x, f1v.y); b0.w = pk2(f1v.z, f1v.w);
    b1.x = pk2(f2v.x, f2v.y); b1.y = pk2(f2v.z, f2v.w);
    b1.z = pk2(f3v.x, f3v.y); b1.w = pk2(f3v.z, f3v.w);
    *(uint4*)(Blds + sr * 32 + sc) = b0;
    *(uint4*)(Blds + sr * 32 + sc + 8) = b1;
    __syncthreads();

    bf16x8 af[4], bb[4];
#pragma unroll
    for (int i = 0; i < 4; ++i) {
      af[i] = *(bf16x8*)(Alds + (wm + i * 16 + cl) * 32 + kg);
      bb[i] = *(bf16x8*)(Blds + (wn + i * 16 + cl) * 32 + kg);
    }
#pragma unroll
    for (int i = 0; i < 4; ++i)
#pragma unroll
      for (int j = 0; j < 4; ++j)
        acc[i][j] = __builtin_amdgcn_mfma_f32_16x16x32_bf16(af[i], bb[j], acc[i][j], 0, 0, 0);
  }

  int rg = (l >> 4) * 4;
#pragma unroll
  for (int j = 0; j < 4; ++j) {
    int n = bn + wn + j * 16 + cl;
    float bias = bih[n] + bhh[n];
#pragma unroll
    for (int i = 0; i < 4; ++i) {
      int m = bm + wm + i * 16 + rg;
#pragma unroll
      for (int r = 0; r < 4; ++r)
        P[(size_t)(m + r) * FOURH + n] = acc[i][j][r] + bias;
    }
  }
}

// ---------------- persistent sequential LSTM ----------------
// BARRIER-FREE: direct register polling (R16) + wave-owns-cells (R4 mapping).
// 256 WGs x 256 threads. WG g owns h rows [g*8, g*8+8); wave G owns 2
// COMPLETE cells (rows g*8+2G, +2G+1, all 4 gates) over all 2048 cols, so
// after the in-wave butterfly it finishes its cells and pushes with NO
// cross-wave exchange: zero __syncthreads and zero LDS in the step loop.
// Global lockstep is enforced by the data dependency itself (each wave's
// poll set spans all 2048 cols = all producer waves).
// hrep[8][2][2048] u32 = (tag16<<16 | f16(h)). Push: lanes 0..7 of each wave
// store the wave's 2 tagged words (dwordx2 sc0 sc1) to replica l. Consumers
// poll their 32 consumed words of replica (g&7) directly into registers
// (8x dwordx4 tagged loads, offset-immediate). Parity double-buffer on t&1;
// overwrite of parity p at t+2 is safe because the detecting load at t IS
// the consuming read (producer of t+2 transitively waited on it).
__launch_bounds__(256, 1)
__global__ void lstm_seq(const float* __restrict__ Whh, const float* __restrict__ P,
                         unsigned* __restrict__ hrep, float* __restrict__ hs,
                         float* __restrict__ out) {
  int g = blockIdx.x;
  int tid = threadIdx.x;
  int G = tid >> 6, l = tid & 63;

  // weights: q = gate*2 + rowbit; row = g*8 + 2G + (q&1); gate = q>>1;
  // cols j*256 + l*4 + 0..3 packed as f16 pairs
  unsigned wpk[8][8][2];
#pragma unroll
  for (int q = 0; q < 8; ++q) {
    const float* wrow = Whh + ((size_t)(q >> 1) * H + g * 8 + 2 * G + (q & 1)) * H;
#pragma unroll
    for (int j = 0; j < 8; ++j) {
      float4 wv = *(const float4*)(wrow + j * 256 + l * 4);
      wpk[q][j][0] = pkf16(wv.x, wv.y);
      wpk[q][j][1] = pkf16(wv.z, wv.w);
    }
  }

  float c_state = 0.f;  // per-lane redundant for row (l&1); lanes 0,1 canonical
  const unsigned* myrep = hrep + (size_t)(g & 7) * 2 * H;
  int row0 = g * 8 + 2 * G;

  for (int t = 0; t < NT; ++t) {
    int p = t & 1;

    // P prefetch: lanes 0..7 of THIS wave -> gate l>>1, rowbit l&1
    float p_v = 0.f;
    if (l < 8)
      p_v = P[(size_t)t * FOURH + (size_t)(l >> 1) * H + row0 + (l & 1)];

    // direct tagged poll of this thread's 32 consumed h-words into regs
    uint4v v0, v1, v2, v3, v4, v5, v6, v7;
    {
      const unsigned* s0 = myrep + (size_t)p * H + l * 4;   // j = 0..3
      const unsigned* s1 = s0 + 1024;                       // j = 4..7
      unsigned want = ((unsigned)t & 0xffffu) << 16;
      for (;;) {
        asm volatile(
            "global_load_dwordx4 %0, %8, off sc0 sc1\n\t"
            "global_load_dwordx4 %1, %8, off offset:1024 sc0 sc1\n\t"
            "global_load_dwordx4 %2, %8, off offset:2048 sc0 sc1\n\t"
            "global_load_dwordx4 %3, %8, off offset:3072 sc0 sc1\n\t"
            "global_load_dwordx4 %4, %9, off sc0 sc1\n\t"
            "global_load_dwordx4 %5, %9, off offset:1024 sc0 sc1\n\t"
            "global_load_dwordx4 %6, %9, off offset:2048 sc0 sc1\n\t"
            "global_load_dwordx4 %7, %9, off offset:3072 sc0 sc1\n\t"
            "s_waitcnt vmcnt(0)"
            : "=&v"(v0), "=&v"(v1), "=&v"(v2), "=&v"(v3),
              "=&v"(v4), "=&v"(v5), "=&v"(v6), "=&v"(v7)
            : "v"(s0), "v"(s1)
            : "memory");
        unsigned m =
            ((v0.x ^ want) | (v0.y ^ want) | (v0.z ^ want) | (v0.w ^ want) |
             (v1.x ^ want) | (v1.y ^ want) | (v1.z ^ want) | (v1.w ^ want) |
             (v2.x ^ want) | (v2.y ^ want) | (v2.z ^ want) | (v2.w ^ want) |
             (v3.x ^ want) | (v3.y ^ want) | (v3.z ^ want) | (v3.w ^ want) |
             (v4.x ^ want) | (v4.y ^ want) | (v4.z ^ want) | (v4.w ^ want) |
             (v5.x ^ want) | (v5.y ^ want) | (v5.z ^ want) | (v5.w ^ want) |
             (v6.x ^ want) | (v6.y ^ want) | (v6.z ^ want) | (v6.w ^ want) |
             (v7.x ^ want) | (v7.y ^ want) | (v7.z ^ want) | (v7.w ^ want)) &
            0xffff0000u;
        if (m == 0) break;
        __builtin_amdgcn_s_sleep(1);
      }
    }

    // matvec from registers: 8 row-gates (2 cells x 4 gates) x 32 cols
    float acc[8] = {0.f, 0.f, 0.f, 0.f, 0.f, 0.f, 0.f, 0.f};
#define JBLK(vj, j)                                               \
  {                                                               \
    unsigned hw0 = (vj.x & 0xffffu) | (vj.y << 16);               \
    unsigned hw1 = (vj.z & 0xffffu) | (vj.w << 16);               \
    _Pragma("unroll") for (int q = 0; q < 8; ++q) {               \
      acc[q] = dot2(wpk[q][j][0], hw0, acc[q]);                   \
      acc[q] = dot2(wpk[q][j][1], hw1, acc[q]);                   \
    }                                                             \
  }
    JBLK(v0, 0) JBLK(v1, 1) JBLK(v2, 2) JBLK(v3, 3)
    JBLK(v4, 4) JBLK(v5, 5) JBLK(v6, 6) JBLK(v7, 7)
#undef JBLK

    // butterfly reduce over the wave (ds_swizzle + final shfl)
#pragma unroll
    for (int q = 0; q < 8; ++q) acc[q] = wave_sum(acc[q]);

    // in-wave cell finish: all lanes redundantly compute row r = l&1
    int r = l & 1;
    float pi = __shfl(p_v, r, 64);
    float pf = __shfl(p_v, 2 + r, 64);
    float pg = __shfl(p_v, 4 + r, 64);
    float po = __shfl(p_v, 6 + r, 64);
    float ai = r ? acc[1] : acc[0];
    float af = r ? acc[3] : acc[2];
    float ag = r ? acc[5] : acc[4];
    float ao = r ? acc[7] : acc[6];

    float iv = sigm(ai + pi);
    float fv = sigm(af + pf);
    float gv = tanh_fast(ag + pg);
    float ov = sigm(ao + po);
    c_state = fv * c_state + iv * gv;
    float hnew = ov * tanh_fast(c_state);
    unsigned wword = ((((unsigned)(t + 1)) & 0xffffu) << 16) | (pkf16(hnew, 0.f) & 0xffffu);

    // push: lanes 0..7 store the wave's 2 words (dwordx2) to replica l
    unsigned u0 = __shfl(wword, 0, 64);
    unsigned u1 = __shfl(wword, 1, 64);
    if (l < 8) {
      unsigned* dst = hrep + ((size_t)l * 2 + ((t + 1) & 1)) * H + row0;
      uint2v V; V.x = u0; V.y = u1;
      asm volatile("global_store_dwordx2 %0, %1, off sc0 sc1"
                   :
                   : "v"(dst), "v"(V)
                   : "memory");
    }
    // off-critical-path bookkeeping: lanes 0,1 own rows row0+l
    if (l < 2) {
      int hidx = row0 + l;
      int m3 = t - (t / 3) * 3;
      if (m3 == 2) hs[(size_t)(t / 3) * H + hidx] = hnew;
      if (t == NT - 1) {
        out[512 + hidx] = hnew;        // hF
        out[512 + H + hidx] = c_state; // cF
      }
    }
  }
}

// ---------------- readout: outputs[256][2] ----------------
__global__ void out_head(const float* __restrict__ hs, const float* __restrict__ Wout,
                         const float* __restrict__ bout, float* __restrict__ out) {
  int s = blockIdx.x;
  int l = threadIdx.x;  // 64
  float a0 = 0.f, a1 = 0.f;
#pragma unroll 4
  for (int j = 0; j < 32; ++j) {
    int idx = j * 64 + l;
    float h = hs[(size_t)s * H + idx];
    a0 += h * Wout[idx];
    a1 += h * Wout[H + idx];
  }
#pragma unroll
  for (int off = 1; off < 64; off <<= 1) {
    a0 += __shfl_xor(a0, off, 64);
    a1 += __shfl_xor(a1, off, 64);
  }
  if (l == 0) {
    out[s * 2]     = a0 + bout[0];
    out[s * 2 + 1] = a1 + bout[1];
  }
}

extern "C" void kernel_launch(void* const* d_in, const int* in_sizes, int n_in,
                              void* d_out, int out_size, void* d_ws, size_t ws_size,
                              hipStream_t stream) {
  const int*   ctx        = (const int*)d_in[0];
  const int*   f1         = (const int*)d_in[1];
  const int*   f2         = (const int*)d_in[2];
  const float* ctx_table  = (const float*)d_in[3];
  const float* face_table = (const float*)d_in[4];
  const float* Wih        = (const float*)d_in[5];
  const float* Whh        = (const float*)d_in[6];
  const float* bih        = (const float*)d_in[7];
  const float* bhh        = (const float*)d_in[8];
  const float* Wout       = (const float*)d_in[9];
  const float* bout       = (const float*)d_in[10];
  float* out = (float*)d_out;

  char* ws = (char*)d_ws;
  size_t off = 0;
  unsigned short* X = (unsigned short*)(ws + off); off += (size_t)NT * H * 2;  // 3,145,728
  float* P    = (float*)(ws + off); off += (size_t)NT * FOURH * 4;             // 25,165,824
  unsigned* hrep = (unsigned*)(ws + off); off += (size_t)8 * 2 * H * 4;        // 131,072
  float* hs   = (float*)(ws + off); off += (size_t)NS * H * 4;                 // 2,097,152

  // zero replicas: parity-0 tag0/value0 = valid t=0 data (h=0); replay-safe
  (void)hipMemsetAsync(hrep, 0, (size_t)8 * 2 * H * 4, stream);

  gather_x<<<NT, 256, 0, stream>>>(ctx, f1, f2, ctx_table, face_table, X);
  gemm_p<<<6 * 64, 256, 0, stream>>>(X, Wih, bih, bhh, P);
  lstm_seq<<<NS, 256, 0, stream>>>(Whh, P, hrep, hs, out);
  out_head<<<NS, 64, 0, stream>>>(hs, Wout, bout, out);
}

// Round 19
// 2193.880 us; speedup vs baseline: 1.7330x; 1.7330x over previous
//
#include <hip/hip_runtime.h>
#include <hip/hip_bf16.h>
#include <stdint.h>

#define H 2048
#define FOURH 8192
#define NT 768
#define NS 256

typedef __attribute__((ext_vector_type(8))) short bf16x8;
typedef __attribute__((ext_vector_type(4))) float f32x4;
typedef __attribute__((ext_vector_type(4))) unsigned uint4v;
typedef _Float16 f16x2 __attribute__((ext_vector_type(2)));

static __device__ __forceinline__ unsigned short f2bf(float x) {
  unsigned u = __float_as_uint(x);
  return (unsigned short)((u + 0x7fffu + ((u >> 16) & 1u)) >> 16);
}
static __device__ __forceinline__ unsigned pk2(float lo, float hi) {
  return ((unsigned)f2bf(hi) << 16) | (unsigned)f2bf(lo);
}
static __device__ __forceinline__ unsigned pkf16(float lo, float hi) {
  auto h = __builtin_amdgcn_cvt_pkrtz(lo, hi);  // __fp16 ext_vector(2)
  return __builtin_bit_cast(unsigned, h);
}
static __device__ __forceinline__ float sigm(float x) { return 1.f / (1.f + __expf(-x)); }
static __device__ __forceinline__ float tanh_fast(float x) {
  float xc = fminf(fmaxf(x, -15.f), 15.f);
  float e = __expf(2.f * xc);
  return (e - 1.f) / (e + 1.f);
}

// dot2: acc += w.x*h.x + w.y*h.y with packed f16 operands
static __device__ __forceinline__ float dot2(unsigned w, unsigned h, float acc) {
#if __has_builtin(__builtin_amdgcn_fdot2)
  return __builtin_amdgcn_fdot2(__builtin_bit_cast(f16x2, w),
                                __builtin_bit_cast(f16x2, h), acc, false);
#else
  f16x2 wv = __builtin_bit_cast(f16x2, w);
  f16x2 hv = __builtin_bit_cast(f16x2, h);
  return acc + (float)wv.x * (float)hv.x + (float)wv.y * (float)hv.y;
#endif
}

// one-immediate-pattern xor swizzle (BitMode: offset = xor<<10 | 0x1F)
template <int PAT>
static __device__ __forceinline__ float swz(float v) {
  return __int_as_float(__builtin_amdgcn_ds_swizzle(__float_as_int(v), PAT));
}
// full 64-lane xor-butterfly sum
static __device__ __forceinline__ float wave_sum(float v) {
  v += swz<0x041F>(v);          // xor 1
  v += swz<0x081F>(v);          // xor 2
  v += swz<0x101F>(v);          // xor 4
  v += swz<0x201F>(v);          // xor 8
  v += swz<0x401F>(v);          // xor 16
  v += __shfl_xor(v, 32, 64);   // xor 32 (crosses 32-lane groups)
  return v;
}

// ---------------- gather: build X_bf16[768][2048] ----------------
__global__ void gather_x(const int* __restrict__ ctx, const int* __restrict__ f1,
                         const int* __restrict__ f2, const float* __restrict__ ctx_table,
                         const float* __restrict__ face_table, unsigned short* __restrict__ X) {
  int t = blockIdx.x;            // 0..767
  int s = t / 3, k = t - 3 * s;  // sample, sub-step
  const float* src;
  if (k == 0)      src = ctx_table  + (size_t)ctx[s] * H;
  else if (k == 1) src = face_table + (size_t)f1[s] * H;
  else             src = face_table + (size_t)f2[s] * H;
  int c = threadIdx.x * 8;
  float4 v0 = *(const float4*)(src + c);
  float4 v1 = *(const float4*)(src + c + 4);
  uint4 o;
  o.x = pk2(v0.x, v0.y); o.y = pk2(v0.z, v0.w);
  o.z = pk2(v1.x, v1.y); o.w = pk2(v1.z, v1.w);
  *(uint4*)(X + (size_t)t * H + c) = o;
}

// ---------------- GEMM: P[768][8192] = X @ W_ih^T + (b_ih + b_hh) ----------------
__launch_bounds__(256)
__global__ void gemm_p(const unsigned short* __restrict__ X, const float* __restrict__ Wih,
                       const float* __restrict__ bih, const float* __restrict__ bhh,
                       float* __restrict__ P) {
  __shared__ unsigned short Alds[128 * 32];
  __shared__ unsigned short Blds[128 * 32];
  int tid = threadIdx.x;
  int bm = (blockIdx.x >> 6) * 128;   // 6 M-tiles
  int bn = (blockIdx.x & 63) * 128;   // 64 N-tiles
  int w = tid >> 6, l = tid & 63;
  int wm = (w >> 1) * 64, wn = (w & 1) * 64;
  int sr = tid >> 1;             // staging row 0..127
  int sc = (tid & 1) * 16;       // staging col 0 / 16
  int cl = l & 15, kg = (l >> 4) * 8;

  f32x4 acc[4][4];
#pragma unroll
  for (int i = 0; i < 4; ++i)
#pragma unroll
    for (int j = 0; j < 4; ++j) acc[i][j] = (f32x4){0.f, 0.f, 0.f, 0.f};

  for (int kt = 0; kt < H; kt += 32) {
    __syncthreads();
    const unsigned short* ap = X + (size_t)(bm + sr) * H + kt + sc;
    uint4 a0 = *(const uint4*)ap;
    uint4 a1 = *(const uint4*)(ap + 8);
    const float* bp = Wih + (size_t)(bn + sr) * H + kt + sc;
    float4 f0 = *(const float4*)bp;
    float4 f1v = *(const float4*)(bp + 4);
    float4 f2v = *(const float4*)(bp + 8);
    float4 f3v = *(const float4*)(bp + 12);
    *(uint4*)(Alds + sr * 32 + sc) = a0;
    *(uint4*)(Alds + sr * 32 + sc + 8) = a1;
    uint4 b0, b1;
    b0.x = pk2(f0.x, f0.y);  b0.y = pk2(f0.z, f0.w);
    b0.z = pk2(f1v.x, f1v.y); b0.w = pk2(f1v.z, f1v.w);
    b1.x = pk2(f2v.x, f2v.y); b1.y = pk2(f2v.z, f2v.w);
    b1.z = pk2(f3v.x, f3v.y); b1.w = pk2(f3v.z, f3v.w);
    *(uint4*)(Blds + sr * 32 + sc) = b0;
    *(uint4*)(Blds + sr * 32 + sc + 8) = b1;
    __syncthreads();

    bf16x8 af[4], bb[4];
#pragma unroll
    for (int i = 0; i < 4; ++i) {
      af[i] = *(bf16x8*)(Alds + (wm + i * 16 + cl) * 32 + kg);
      bb[i] = *(bf16x8*)(Blds + (wn + i * 16 + cl) * 32 + kg);
    }
#pragma unroll
    for (int i = 0; i < 4; ++i)
#pragma unroll
      for (int j = 0; j < 4; ++j)
        acc[i][j] = __builtin_amdgcn_mfma_f32_16x16x32_bf16(af[i], bb[j], acc[i][j], 0, 0, 0);
  }

  int rg = (l >> 4) * 4;
#pragma unroll
  for (int j = 0; j < 4; ++j) {
    int n = bn + wn + j * 16 + cl;
    float bias = bih[n] + bhh[n];
#pragma unroll
    for (int i = 0; i < 4; ++i) {
      int m = bm + wm + i * 16 + rg;
#pragma unroll
      for (int r = 0; r < 4; ++r)
        P[(size_t)(m + r) * FOURH + n] = acc[i][j][r] + bias;
    }
  }
}

// ---------------- persistent sequential LSTM ----------------
// FINAL (R16 structure, best verified 2.19 ms): push replication + direct
// register polling + packed-f16 dot2 matvec + ds_swizzle butterfly.
// hrep[8][2][2048] u32 = (tag16<<16 | f16(h)). Producers: wave 0 lanes 0..7
// push the WG's 8 contiguous tagged words to all 8 replicas (2x dwordx4
// sc0 sc1 -- one coalesced 32B slot per replica; fragmenting this store was
// a 1.6x regression twice, R10/R17). Consumers: thread (G,l) polls exactly
// its 32 consumed h-words (cols j*256+l*4..+3) of replica (g&7) directly
// into registers -- no LDS staging, no stage barrier; per-thread detection.
// ONE barrier per step (cross-wave gates handoff via gates_lds, parity-
// double-buffered). Remaining per-step cost is the cross-die broadcast
// latency chain (store-visibility + poll RT), not bandwidth or compute:
// all traffic-shaping levers measured null (R2/R4/R6/R8/R14); pipelined
// vmcnt polling is unsound at HIP level (R18, watchdog crash).
__launch_bounds__(256, 1)
__global__ void lstm_seq(const float* __restrict__ Whh, const float* __restrict__ P,
                         unsigned* __restrict__ hrep, float* __restrict__ hs,
                         float* __restrict__ out) {
  __shared__ float gates_lds[2][32];
  int g = blockIdx.x;
  int tid = threadIdx.x;
  int G = tid >> 6, l = tid & 63;

  // one-time weight load: rows G*2048 + g*8 + q, cols j*256 + l*4 + 0..3
  // packed as f16 pairs (even col in low half, matching h packing)
  unsigned wpk[8][8][2];
#pragma unroll
  for (int q = 0; q < 8; ++q) {
    const float* wrow = Whh + (size_t)(G * H + g * 8 + q) * H;
#pragma unroll
    for (int j = 0; j < 8; ++j) {
      float4 wv = *(const float4*)(wrow + j * 256 + l * 4);
      wpk[q][j][0] = pkf16(wv.x, wv.y);
      wpk[q][j][1] = pkf16(wv.z, wv.w);
    }
  }

  float c_state = 0.f;  // valid on wave-0 lanes 0..7
  const unsigned* myrep = hrep + (size_t)(g & 7) * 2 * H;

  for (int t = 0; t < NT; ++t) {
    int p = t & 1;

    // independent P-row fetch first (overlaps the poll); wave 0 only
    float p_v = 0.f;
    if (tid < 32)
      p_v = P[(size_t)t * FOURH + (size_t)(tid >> 3) * H + g * 8 + (tid & 7)];

    // direct tagged poll of this thread's 32 consumed h-words into regs
    uint4v v0, v1, v2, v3, v4, v5, v6, v7;
    {
      const unsigned* s0 = myrep + (size_t)p * H + l * 4;   // j = 0..3
      const unsigned* s1 = s0 + 1024;                       // j = 4..7
      unsigned want = ((unsigned)t & 0xffffu) << 16;
      for (;;) {
        asm volatile(
            "global_load_dwordx4 %0, %8, off sc0 sc1\n\t"
            "global_load_dwordx4 %1, %8, off offset:1024 sc0 sc1\n\t"
            "global_load_dwordx4 %2, %8, off offset:2048 sc0 sc1\n\t"
            "global_load_dwordx4 %3, %8, off offset:3072 sc0 sc1\n\t"
            "global_load_dwordx4 %4, %9, off sc0 sc1\n\t"
            "global_load_dwordx4 %5, %9, off offset:1024 sc0 sc1\n\t"
            "global_load_dwordx4 %6, %9, off offset:2048 sc0 sc1\n\t"
            "global_load_dwordx4 %7, %9, off offset:3072 sc0 sc1\n\t"
            "s_waitcnt vmcnt(0)"
            : "=&v"(v0), "=&v"(v1), "=&v"(v2), "=&v"(v3),
              "=&v"(v4), "=&v"(v5), "=&v"(v6), "=&v"(v7)
            : "v"(s0), "v"(s1)
            : "memory");
        unsigned m =
            ((v0.x ^ want) | (v0.y ^ want) | (v0.z ^ want) | (v0.w ^ want) |
             (v1.x ^ want) | (v1.y ^ want) | (v1.z ^ want) | (v1.w ^ want) |
             (v2.x ^ want) | (v2.y ^ want) | (v2.z ^ want) | (v2.w ^ want) |
             (v3.x ^ want) | (v3.y ^ want) | (v3.z ^ want) | (v3.w ^ want) |
             (v4.x ^ want) | (v4.y ^ want) | (v4.z ^ want) | (v4.w ^ want) |
             (v5.x ^ want) | (v5.y ^ want) | (v5.z ^ want) | (v5.w ^ want) |
             (v6.x ^ want) | (v6.y ^ want) | (v6.z ^ want) | (v6.w ^ want) |
             (v7.x ^ want) | (v7.y ^ want) | (v7.z ^ want) | (v7.w ^ want)) &
            0xffff0000u;
        if (m == 0) break;
        __builtin_amdgcn_s_sleep(1);
      }
    }

    // matvec from registers: 8 row-gates x 32 cols per thread
    float acc[8] = {0.f, 0.f, 0.f, 0.f, 0.f, 0.f, 0.f, 0.f};
#define JBLK(vj, j)                                               \
  {                                                               \
    unsigned hw0 = (vj.x & 0xffffu) | (vj.y << 16);               \
    unsigned hw1 = (vj.z & 0xffffu) | (vj.w << 16);               \
    _Pragma("unroll") for (int q = 0; q < 8; ++q) {               \
      acc[q] = dot2(wpk[q][j][0], hw0, acc[q]);                   \
      acc[q] = dot2(wpk[q][j][1], hw1, acc[q]);                   \
    }                                                             \
  }
    JBLK(v0, 0) JBLK(v1, 1) JBLK(v2, 2) JBLK(v3, 3)
    JBLK(v4, 4) JBLK(v5, 5) JBLK(v6, 6) JBLK(v7, 7)
#undef JBLK

    // butterfly reduce over the wave (ds_swizzle + final shfl)
#pragma unroll
    for (int q = 0; q < 8; ++q) acc[q] = wave_sum(acc[q]);
    if (l == 0) {
#pragma unroll
      for (int q = 0; q < 8; ++q) gates_lds[p][G * 8 + q] = acc[q];
    }
    __syncthreads();

    // wave 0: gate finish on lanes 0..7, PUSH to all 8 replicas, bookkeeping
    if (tid < 64) {
      int q = tid & 7;
      float pre_i = __shfl(p_v, q, 64);
      float pre_f = __shfl(p_v, 8 + q, 64);
      float pre_g = __shfl(p_v, 16 + q, 64);
      float pre_o = __shfl(p_v, 24 + q, 64);
      unsigned wword = 0;
      float hnew = 0.f;
      if (l < 8) {
        float iv = sigm(gates_lds[p][q]      + pre_i);
        float fv = sigm(gates_lds[p][8 + q]  + pre_f);
        float gv = tanh_fast(gates_lds[p][16 + q] + pre_g);
        float ov = sigm(gates_lds[p][24 + q] + pre_o);
        c_state = fv * c_state + iv * gv;
        hnew = ov * tanh_fast(c_state);
        wword = ((((unsigned)(t + 1)) & 0xffffu) << 16) | (pkf16(hnew, 0.f) & 0xffffu);
      }
      unsigned w0 = __shfl(wword, 0, 64), w1 = __shfl(wword, 1, 64);
      unsigned w2 = __shfl(wword, 2, 64), w3 = __shfl(wword, 3, 64);
      unsigned w4 = __shfl(wword, 4, 64), w5 = __shfl(wword, 5, 64);
      unsigned w6 = __shfl(wword, 6, 64), w7 = __shfl(wword, 7, 64);
      if (l < 8) {
        unsigned* dst = hrep + ((size_t)l * 2 + ((t + 1) & 1)) * H + g * 8;
        uint4v A, B;
        A.x = w0; A.y = w1; A.z = w2; A.w = w3;
        B.x = w4; B.y = w5; B.z = w6; B.w = w7;
        asm volatile(
            "global_store_dwordx4 %0, %2, off sc0 sc1\n\t"
            "global_store_dwordx4 %1, %3, off sc0 sc1"
            :
            : "v"(dst), "v"(dst + 4), "v"(A), "v"(B)
            : "memory");
        // off-critical-path bookkeeping
        int m3 = t - (t / 3) * 3;
        if (m3 == 2) hs[(size_t)(t / 3) * H + g * 8 + q] = hnew;
        if (t == NT - 1) {
          out[512 + g * 8 + q] = hnew;        // hF
          out[512 + H + g * 8 + q] = c_state; // cF
        }
      }
    }
  }
}

// ---------------- readout: outputs[256][2] ----------------
__global__ void out_head(const float* __restrict__ hs, const float* __restrict__ Wout,
                         const float* __restrict__ bout, float* __restrict__ out) {
  int s = blockIdx.x;
  int l = threadIdx.x;  // 64
  float a0 = 0.f, a1 = 0.f;
#pragma unroll 4
  for (int j = 0; j < 32; ++j) {
    int idx = j * 64 + l;
    float h = hs[(size_t)s * H + idx];
    a0 += h * Wout[idx];
    a1 += h * Wout[H + idx];
  }
#pragma unroll
  for (int off = 1; off < 64; off <<= 1) {
    a0 += __shfl_xor(a0, off, 64);
    a1 += __shfl_xor(a1, off, 64);
  }
  if (l == 0) {
    out[s * 2]     = a0 + bout[0];
    out[s * 2 + 1] = a1 + bout[1];
  }
}

extern "C" void kernel_launch(void* const* d_in, const int* in_sizes, int n_in,
                              void* d_out, int out_size, void* d_ws, size_t ws_size,
                              hipStream_t stream) {
  const int*   ctx        = (const int*)d_in[0];
  const int*   f1         = (const int*)d_in[1];
  const int*   f2         = (const int*)d_in[2];
  const float* ctx_table  = (const float*)d_in[3];
  const float* face_table = (const float*)d_in[4];
  const float* Wih        = (const float*)d_in[5];
  const float* Whh        = (const float*)d_in[6];
  const float* bih        = (const float*)d_in[7];
  const float* bhh        = (const float*)d_in[8];
  const float* Wout       = (const float*)d_in[9];
  const float* bout       = (const float*)d_in[10];
  float* out = (float*)d_out;

  char* ws = (char*)d_ws;
  size_t off = 0;
  unsigned short* X = (unsigned short*)(ws + off); off += (size_t)NT * H * 2;  // 3,145,728
  float* P    = (float*)(ws + off); off += (size_t)NT * FOURH * 4;             // 25,165,824
  unsigned* hrep = (unsigned*)(ws + off); off += (size_t)8 * 2 * H * 4;        // 131,072
  float* hs   = (float*)(ws + off); off += (size_t)NS * H * 4;                 // 2,097,152

  // zero replicas: parity-0 tag0/value0 = valid t=0 data (h=0); replay-safe
  (void)hipMemsetAsync(hrep, 0, (size_t)8 * 2 * H * 4, stream);

  gather_x<<<NT, 256, 0, stream>>>(ctx, f1, f2, ctx_table, face_table, X);
  gemm_p<<<6 * 64, 256, 0, stream>>>(X, Wih, bih, bhh, P);
  lstm_seq<<<NS, 256, 0, stream>>>(Whh, P, hrep, hs, out);
  out_head<<<NS, 64, 0, stream>>>(hs, Wout, bout, out);
}